// Round 2
// baseline (163.416 us; speedup 1.0000x reference)
//
#include <hip/hip_runtime.h>
#include <math.h>

#define QN 128
#define SN 512
#define DN 768
#define TDN 1536
#define CN 64

// ws layout (floats):
//   hqp: 2 * QN*TDN   (split-K partials for hq)
//   hsp: 2 * SN*TDN   (split-K partials for hs)
//   aggbuf: QN*CN     (label-segmented sums, zeroed via hipMemsetAsync)
#define HQP_ELEMS (2 * QN * TDN)
#define HSP_ELEMS (2 * SN * TDN)

// ---------------------------------------------------------------------------
// GEMM: C[m][n] = sum_k A[m][k] * W1[n][Koff + k]   (split-K into 2 halves)
// grid (24, 10, 2). block 256 (16x16), micro 4x4, LDS transposed [kk][m],
// double-buffered (1 barrier per K-step) with register prefetch of the next
// global tile so the load latency hides under the 512-cyc FMA block.
// ---------------------------------------------------------------------------
__global__ __launch_bounds__(256) void gemm_split_kernel(
    const float* __restrict__ query, const float* __restrict__ support,
    const float* __restrict__ W1, float* __restrict__ hqp, float* __restrict__ hsp)
{
    const int nt = blockIdx.x;   // 0..23
    const int mt = blockIdx.y;   // 0..9
    const int kz = blockIdx.z;   // 0..1

    const float* A;
    float* Cout;
    int M0, Koff;
    if (mt < 2) { A = query;   M0 = mt * 64;       Koff = 0;  Cout = hqp + (size_t)kz * QN * TDN; }
    else        { A = support; M0 = (mt - 2) * 64; Koff = DN; Cout = hsp + (size_t)kz * SN * TDN; }

    const int tid  = threadIdx.x;
    const int tx   = tid & 15;
    const int ty   = tid >> 4;
    const int lrow = tid >> 2;   // 0..63
    const int lq   = tid & 3;    // 0..3

    __shared__ float As[2][16][68];
    __shared__ float Bs[2][16][68];

    float acc[4][4];
    #pragma unroll
    for (int i = 0; i < 4; ++i)
        #pragma unroll
        for (int j = 0; j < 4; ++j) acc[i][j] = 0.0f;

    const float* Aptr = &A [(size_t)(M0 + lrow) * DN  + kz * 384 + lq * 4];
    const float* Bptr = &W1[(size_t)(nt * 64 + lrow) * TDN + Koff + kz * 384 + lq * 4];

    // prologue: stage k-step 0 into buffer 0
    {
        float4 av = *(const float4*)(Aptr);
        float4 bv = *(const float4*)(Bptr);
        As[0][lq*4+0][lrow] = av.x; As[0][lq*4+1][lrow] = av.y;
        As[0][lq*4+2][lrow] = av.z; As[0][lq*4+3][lrow] = av.w;
        Bs[0][lq*4+0][lrow] = bv.x; Bs[0][lq*4+1][lrow] = bv.y;
        Bs[0][lq*4+2][lrow] = bv.z; Bs[0][lq*4+3][lrow] = bv.w;
    }
    __syncthreads();

    int buf = 0;
    for (int it = 0; it < 24; ++it) {
        float4 av, bv;
        if (it < 23) {                     // issue next tile's loads early
            av = *(const float4*)(Aptr + (it + 1) * 16);
            bv = *(const float4*)(Bptr + (it + 1) * 16);
        }
        #pragma unroll
        for (int kk = 0; kk < 16; ++kk) {
            float4 a4 = *(const float4*)&As[buf][kk][ty * 4];
            float4 b4 = *(const float4*)&Bs[buf][kk][tx * 4];
            float a[4] = {a4.x, a4.y, a4.z, a4.w};
            float b[4] = {b4.x, b4.y, b4.z, b4.w};
            #pragma unroll
            for (int i = 0; i < 4; ++i)
                #pragma unroll
                for (int j = 0; j < 4; ++j)
                    acc[i][j] += a[i] * b[j];
        }
        if (it < 23) {
            int nb = buf ^ 1;
            As[nb][lq*4+0][lrow] = av.x; As[nb][lq*4+1][lrow] = av.y;
            As[nb][lq*4+2][lrow] = av.z; As[nb][lq*4+3][lrow] = av.w;
            Bs[nb][lq*4+0][lrow] = bv.x; Bs[nb][lq*4+1][lrow] = bv.y;
            Bs[nb][lq*4+2][lrow] = bv.z; Bs[nb][lq*4+3][lrow] = bv.w;
            __syncthreads();
            buf = nb;
        }
    }

    #pragma unroll
    for (int i = 0; i < 4; ++i) {
        float4 v = make_float4(acc[i][0], acc[i][1], acc[i][2], acc[i][3]);
        *(float4*)&Cout[(size_t)(M0 + ty * 4 + i) * TDN + nt * 64 + tx * 4] = v;
    }
}

// ---------------------------------------------------------------------------
// Score + label-segmented reduce, fused.
// grid (16, 2, 8): jc (96 j's), q-tile(64), s-tile(64). block 256, micro 4x4.
// Stage hq/hs transposed [jj][row] (split-K partials summed, b1 folded into
// hq). Compute 64x64 relu-dot tile, spill to LDS, then run-length reduce each
// q-row by label and atomicAdd into aggbuf[q][c] (zeroed by host memset).
// ---------------------------------------------------------------------------
__global__ __launch_bounds__(256) void score_kernel(
    const float* __restrict__ hqp, const float* __restrict__ hsp,
    const float* __restrict__ b1, const float* __restrict__ W2,
    const int* __restrict__ labels, float* __restrict__ aggbuf)
{
    const int jc = blockIdx.x;   // 0..15
    const int qt = blockIdx.y;   // 0..1
    const int st = blockIdx.z;   // 0..7

    __shared__ float hqT[96][64];
    __shared__ float hsT[96][64];
    __shared__ float w2s[96];
    __shared__ float sc[64][68];
    __shared__ int   lab[64];

    const int tid = threadIdx.x;

    if (tid < 64) lab[tid] = labels[st * 64 + tid];

    #pragma unroll
    for (int l = 0; l < 6; ++l) {
        int idx  = tid + l * 256;         // 0..1535
        int row  = idx / 24;              // 0..63
        int quad = idx - row * 24;        // 0..23
        int j    = jc * 96 + quad * 4;
        float4 h0 = *(const float4*)&hqp[(size_t)(qt * 64 + row) * TDN + j];
        float4 h1 = *(const float4*)&hqp[(size_t)QN * TDN + (size_t)(qt * 64 + row) * TDN + j];
        float4 bb = *(const float4*)&b1[j];
        hqT[quad*4+0][row] = h0.x + h1.x + bb.x;
        hqT[quad*4+1][row] = h0.y + h1.y + bb.y;
        hqT[quad*4+2][row] = h0.z + h1.z + bb.z;
        hqT[quad*4+3][row] = h0.w + h1.w + bb.w;
        float4 g0 = *(const float4*)&hsp[(size_t)(st * 64 + row) * TDN + j];
        float4 g1 = *(const float4*)&hsp[(size_t)SN * TDN + (size_t)(st * 64 + row) * TDN + j];
        hsT[quad*4+0][row] = g0.x + g1.x;
        hsT[quad*4+1][row] = g0.y + g1.y;
        hsT[quad*4+2][row] = g0.z + g1.z;
        hsT[quad*4+3][row] = g0.w + g1.w;
    }
    if (tid < 24) {
        float4 w = *(const float4*)&W2[jc * 96 + tid * 4];
        w2s[tid*4+0] = w.x; w2s[tid*4+1] = w.y;
        w2s[tid*4+2] = w.z; w2s[tid*4+3] = w.w;
    }
    __syncthreads();

    const int tx = tid & 15;
    const int ty = tid >> 4;
    float acc[4][4];
    #pragma unroll
    for (int i = 0; i < 4; ++i)
        #pragma unroll
        for (int j = 0; j < 4; ++j) acc[i][j] = 0.0f;

    #pragma unroll 4
    for (int jj = 0; jj < 96; ++jj) {
        float4 a4 = *(const float4*)&hqT[jj][ty * 4];
        float4 b4 = *(const float4*)&hsT[jj][tx * 4];
        float w = w2s[jj];
        float a[4] = {a4.x, a4.y, a4.z, a4.w};
        float b[4] = {b4.x, b4.y, b4.z, b4.w};
        #pragma unroll
        for (int i = 0; i < 4; ++i)
            #pragma unroll
            for (int j = 0; j < 4; ++j)
                acc[i][j] += w * fmaxf(a[i] + b[j], 0.0f);
    }

    #pragma unroll
    for (int i = 0; i < 4; ++i) {
        float4 v = make_float4(acc[i][0], acc[i][1], acc[i][2], acc[i][3]);
        *(float4*)&sc[ty * 4 + i][tx * 4] = v;
    }
    __syncthreads();

    // run-length label reduce: thread = (q-row, 16-wide s segment)
    {
        int row = tid >> 2;          // 0..63
        int seg = tid & 3;           // 0..3
        float* aggrow = aggbuf + (size_t)(qt * 64 + row) * CN;
        int   runc = lab[seg * 16];
        float runv = 0.0f;
        #pragma unroll
        for (int k = 0; k < 16; ++k) {
            int s = seg * 16 + k;
            int c = lab[s];
            if (c != runc) {
                atomicAdd(&aggrow[runc], runv);
                runv = 0.0f; runc = c;
            }
            runv += sc[row][s];
        }
        atomicAdd(&aggrow[runc], runv);
    }
}

// ---------------------------------------------------------------------------
// Finale: counts histogram, per-query mean, log_softmax, argmax (lower index
// wins), loss. 1 block x 256 threads = 4 wave-groups x 32 q-iterations.
// ---------------------------------------------------------------------------
__global__ __launch_bounds__(256) void finale_kernel(
    const float* __restrict__ aggbuf, const int* __restrict__ labels,
    const int* __restrict__ tgt, float* __restrict__ out)
{
    __shared__ float cnt[CN];
    __shared__ float lsum[4];

    const int tid = threadIdx.x;
    if (tid < CN) cnt[tid] = 0.0f;
    __syncthreads();
    atomicAdd(&cnt[labels[tid]],       1.0f);
    atomicAdd(&cnt[labels[tid + 256]], 1.0f);
    __syncthreads();

    const int g    = tid >> 6;   // 0..3
    const int lane = tid & 63;
    float myloss = 0.0f;

    for (int it = 0; it < 32; ++it) {
        int q = it * 4 + g;
        float v = aggbuf[(size_t)q * CN + lane] / fmaxf(cnt[lane], 1.0f);
        // max
        float m = v;
        #pragma unroll
        for (int off = 1; off < 64; off <<= 1)
            m = fmaxf(m, __shfl_xor(m, off));
        // argmax, lower index wins ties
        float av = v; int am = lane;
        #pragma unroll
        for (int off = 1; off < 64; off <<= 1) {
            float ov = __shfl_xor(av, off);
            int   oi = __shfl_xor(am, off);
            if (ov > av || (ov == av && oi < am)) { av = ov; am = oi; }
        }
        // sum exp
        float e = expf(v - m);
        #pragma unroll
        for (int off = 1; off < 64; off <<= 1)
            e += __shfl_xor(e, off);
        int t = tgt[q];
        float vt = __shfl(v, t, 64);
        if (lane == 0) {
            myloss += -(vt - m - logf(e));
            out[1 + q] = (am == t) ? 1.0f : 0.0f;
        }
    }
    if (lane == 0) lsum[g] = myloss;
    __syncthreads();
    if (tid == 0)
        out[0] = (lsum[0] + lsum[1] + lsum[2] + lsum[3]) / (float)QN;
}

extern "C" void kernel_launch(void* const* d_in, const int* in_sizes, int n_in,
                              void* d_out, int out_size, void* d_ws, size_t ws_size,
                              hipStream_t stream) {
    const float* query   = (const float*)d_in[0];
    const float* support = (const float*)d_in[1];
    const float* W1      = (const float*)d_in[2];
    const float* b1      = (const float*)d_in[3];
    const float* W2      = (const float*)d_in[4];
    // d_in[5] = b2: cancels exactly under log_softmax/argmax (uniform shift) -> unused
    const int* labels = (const int*)d_in[6];
    const int* tgt    = (const int*)d_in[7];
    // d_in[8] = num_classes (compile-time 64)

    float* ws     = (float*)d_ws;
    float* hqp    = ws;                    // 2*QN*TDN
    float* hsp    = hqp + HQP_ELEMS;       // 2*SN*TDN
    float* aggbuf = hsp + HSP_ELEMS;       // QN*CN
    float* out    = (float*)d_out;

    hipMemsetAsync(aggbuf, 0, (size_t)QN * CN * sizeof(float), stream);
    hipLaunchKernelGGL(gemm_split_kernel, dim3(24, 10, 2), dim3(256), 0, stream,
                       query, support, W1, hqp, hsp);
    hipLaunchKernelGGL(score_kernel, dim3(16, 2, 8), dim3(256), 0, stream,
                       hqp, hsp, b1, W2, labels, aggbuf);
    hipLaunchKernelGGL(finale_kernel, dim3(1), dim3(256), 0, stream,
                       aggbuf, labels, tgt, out);
}

// Round 3
// 133.594 us; speedup vs baseline: 1.2232x; 1.2232x over previous
//
#include <hip/hip_runtime.h>
#include <math.h>

#define QN 128
#define SN 512
#define DN 768
#define TDN 1536
#define CN 64
#define KSPLIT 4
#define KCH 192   // 768 / KSPLIT

// ws layout (floats): hqp | hsp | aggbuf | lossp  (aggbuf+lossp zeroed by gemm)
#define HQP_ELEMS (KSPLIT * QN * TDN)
#define HSP_ELEMS (KSPLIT * SN * TDN)
#define ZERO_ELEMS (QN * CN + QN)

// ---------------------------------------------------------------------------
// GEMM: out[m][n] = sum_k A[m][k] * W1[n][Koff+k], split-K 4.
// grid (12, 5, 4): x = n-tile(128), y: 0=hq(128 rows), 1..4=hs row-tiles(128),
// z = K chunk (192). block 256, micro 8x8 (rows ty*4+i / 64+ty*4+i, cols
// tx*4+j / 64+tx*4+j so every LDS read is a float4 at 16B stride: 2-way bank
// alias = free). LDS [kk][m] transposed, double-buffered, register prefetch.
// Blocks (nt==0, kz==0) also zero aggbuf+lossp for the later kernels.
// ---------------------------------------------------------------------------
__global__ __launch_bounds__(256) void gemm_kernel(
    const float* __restrict__ query, const float* __restrict__ support,
    const float* __restrict__ W1, float* __restrict__ hqp, float* __restrict__ hsp,
    float* __restrict__ zbuf)
{
    const int nt = blockIdx.x;   // 0..11
    const int mt = blockIdx.y;   // 0..4
    const int kz = blockIdx.z;   // 0..3
    const int tid = threadIdx.x;

    if (nt == 0 && kz == 0) {    // zero aggbuf+lossp (5 blocks x 256 thr x 8 f)
        int o = (mt * 256 + tid) * 8;
        if (o < ZERO_ELEMS) {
            *(float4*)&zbuf[o]     = make_float4(0.f, 0.f, 0.f, 0.f);
            *(float4*)&zbuf[o + 4] = make_float4(0.f, 0.f, 0.f, 0.f);
        }
    }

    const float* A;
    float* Cout;
    int M0, Koff;
    if (mt == 0) { A = query;   M0 = 0;              Koff = 0;  Cout = hqp + (size_t)kz * QN * TDN; }
    else         { A = support; M0 = (mt - 1) * 128; Koff = DN; Cout = hsp + (size_t)kz * SN * TDN; }

    __shared__ float As[2][16][128];
    __shared__ float Bs[2][16][128];

    const int m   = tid >> 1;          // 0..127 staging row
    const int kkb = (tid & 1) * 8;     // k-half within 16-wide step

    const float* Aptr = &A [(size_t)(M0 + m) * DN  + kz * KCH + kkb];
    const float* Bptr = &W1[(size_t)(nt * 128 + m) * TDN + Koff + kz * KCH + kkb];

    float acc[8][8];
    #pragma unroll
    for (int i = 0; i < 8; ++i)
        #pragma unroll
        for (int j = 0; j < 8; ++j) acc[i][j] = 0.0f;

    // prologue: stage step 0
    {
        float4 a0 = *(const float4*)(Aptr);
        float4 a1 = *(const float4*)(Aptr + 4);
        float4 b0 = *(const float4*)(Bptr);
        float4 b1 = *(const float4*)(Bptr + 4);
        As[0][kkb+0][m] = a0.x; As[0][kkb+1][m] = a0.y; As[0][kkb+2][m] = a0.z; As[0][kkb+3][m] = a0.w;
        As[0][kkb+4][m] = a1.x; As[0][kkb+5][m] = a1.y; As[0][kkb+6][m] = a1.z; As[0][kkb+7][m] = a1.w;
        Bs[0][kkb+0][m] = b0.x; Bs[0][kkb+1][m] = b0.y; Bs[0][kkb+2][m] = b0.z; Bs[0][kkb+3][m] = b0.w;
        Bs[0][kkb+4][m] = b1.x; Bs[0][kkb+5][m] = b1.y; Bs[0][kkb+6][m] = b1.z; Bs[0][kkb+7][m] = b1.w;
    }
    __syncthreads();

    const int tx = tid & 15;
    const int ty = tid >> 4;

    int buf = 0;
    for (int it = 0; it < 12; ++it) {
        float4 a0, a1, b0, b1;
        if (it < 11) {
            a0 = *(const float4*)(Aptr + (it + 1) * 16);
            a1 = *(const float4*)(Aptr + (it + 1) * 16 + 4);
            b0 = *(const float4*)(Bptr + (it + 1) * 16);
            b1 = *(const float4*)(Bptr + (it + 1) * 16 + 4);
        }
        #pragma unroll
        for (int kk = 0; kk < 16; ++kk) {
            float4 av0 = *(const float4*)&As[buf][kk][ty * 4];
            float4 av1 = *(const float4*)&As[buf][kk][64 + ty * 4];
            float4 bv0 = *(const float4*)&Bs[buf][kk][tx * 4];
            float4 bv1 = *(const float4*)&Bs[buf][kk][64 + tx * 4];
            float a[8] = {av0.x, av0.y, av0.z, av0.w, av1.x, av1.y, av1.z, av1.w};
            float b[8] = {bv0.x, bv0.y, bv0.z, bv0.w, bv1.x, bv1.y, bv1.z, bv1.w};
            #pragma unroll
            for (int i = 0; i < 8; ++i)
                #pragma unroll
                for (int j = 0; j < 8; ++j)
                    acc[i][j] += a[i] * b[j];
        }
        if (it < 11) {
            int nb = buf ^ 1;
            As[nb][kkb+0][m] = a0.x; As[nb][kkb+1][m] = a0.y; As[nb][kkb+2][m] = a0.z; As[nb][kkb+3][m] = a0.w;
            As[nb][kkb+4][m] = a1.x; As[nb][kkb+5][m] = a1.y; As[nb][kkb+6][m] = a1.z; As[nb][kkb+7][m] = a1.w;
            Bs[nb][kkb+0][m] = b0.x; Bs[nb][kkb+1][m] = b0.y; Bs[nb][kkb+2][m] = b0.z; Bs[nb][kkb+3][m] = b0.w;
            Bs[nb][kkb+4][m] = b1.x; Bs[nb][kkb+5][m] = b1.y; Bs[nb][kkb+6][m] = b1.z; Bs[nb][kkb+7][m] = b1.w;
            __syncthreads();
            buf = nb;
        }
    }

    #pragma unroll
    for (int i = 0; i < 8; ++i) {
        int row = M0 + ((i < 4) ? (ty * 4 + i) : (64 + ty * 4 + i - 4));
        float4 lo = make_float4(acc[i][0], acc[i][1], acc[i][2], acc[i][3]);
        float4 hi = make_float4(acc[i][4], acc[i][5], acc[i][6], acc[i][7]);
        *(float4*)&Cout[(size_t)row * TDN + nt * 128 + tx * 4]      = lo;
        *(float4*)&Cout[(size_t)row * TDN + nt * 128 + 64 + tx * 4] = hi;
    }
}

// ---------------------------------------------------------------------------
// Score + label-segmented reduce, fused. grid (16, 2, 8): jc (96 j), q-tile 64,
// s-tile 64. Stages hq/hs transposed [jj][row] (4 split-K partials summed, b1
// folded into hq), 64x64 relu-dot tile (4x4 micro), spill to LDS, run-length
// label reduce, atomicAdd into aggbuf[q][c] (zeroed by gemm).
// ---------------------------------------------------------------------------
__global__ __launch_bounds__(256) void score_kernel(
    const float* __restrict__ hqp, const float* __restrict__ hsp,
    const float* __restrict__ b1, const float* __restrict__ W2,
    const int* __restrict__ labels, float* __restrict__ aggbuf)
{
    const int jc = blockIdx.x;   // 0..15
    const int qt = blockIdx.y;   // 0..1
    const int st = blockIdx.z;   // 0..7

    __shared__ float hqT[96][64];
    __shared__ float hsT[96][64];
    __shared__ float w2s[96];
    __shared__ float sc[64][68];
    __shared__ int   lab[64];

    const int tid = threadIdx.x;
    if (tid < 64) lab[tid] = labels[st * 64 + tid];

    #pragma unroll
    for (int l = 0; l < 6; ++l) {
        int idx  = tid + l * 256;         // 0..1535
        int row  = idx / 24;              // 0..63
        int quad = idx - row * 24;        // 0..23
        int j    = jc * 96 + quad * 4;
        float4 hv = *(const float4*)&b1[j];
        float4 sv = make_float4(0.f, 0.f, 0.f, 0.f);
        #pragma unroll
        for (int p = 0; p < KSPLIT; ++p) {
            float4 h = *(const float4*)&hqp[(size_t)p * QN * TDN + (size_t)(qt * 64 + row) * TDN + j];
            float4 g = *(const float4*)&hsp[(size_t)p * SN * TDN + (size_t)(st * 64 + row) * TDN + j];
            hv.x += h.x; hv.y += h.y; hv.z += h.z; hv.w += h.w;
            sv.x += g.x; sv.y += g.y; sv.z += g.z; sv.w += g.w;
        }
        hqT[quad*4+0][row] = hv.x; hqT[quad*4+1][row] = hv.y;
        hqT[quad*4+2][row] = hv.z; hqT[quad*4+3][row] = hv.w;
        hsT[quad*4+0][row] = sv.x; hsT[quad*4+1][row] = sv.y;
        hsT[quad*4+2][row] = sv.z; hsT[quad*4+3][row] = sv.w;
    }
    if (tid < 24) {
        float4 w = *(const float4*)&W2[jc * 96 + tid * 4];
        w2s[tid*4+0] = w.x; w2s[tid*4+1] = w.y;
        w2s[tid*4+2] = w.z; w2s[tid*4+3] = w.w;
    }
    __syncthreads();

    const int tx = tid & 15;
    const int ty = tid >> 4;
    float acc[4][4];
    #pragma unroll
    for (int i = 0; i < 4; ++i)
        #pragma unroll
        for (int j = 0; j < 4; ++j) acc[i][j] = 0.0f;

    #pragma unroll 4
    for (int jj = 0; jj < 96; ++jj) {
        float4 a4 = *(const float4*)&hqT[jj][ty * 4];
        float4 b4 = *(const float4*)&hsT[jj][tx * 4];
        float w = w2s[jj];
        float a[4] = {a4.x, a4.y, a4.z, a4.w};
        float b[4] = {b4.x, b4.y, b4.z, b4.w};
        #pragma unroll
        for (int i = 0; i < 4; ++i)
            #pragma unroll
            for (int j = 0; j < 4; ++j)
                acc[i][j] += w * fmaxf(a[i] + b[j], 0.0f);
    }

    #pragma unroll
    for (int i = 0; i < 4; ++i)
        *(float4*)&sc[ty * 4 + i][tx * 4] =
            make_float4(acc[i][0], acc[i][1], acc[i][2], acc[i][3]);
    __syncthreads();

    {   // run-length label reduce: thread = (q-row, 16-wide s segment)
        int row = tid >> 2;
        int seg = tid & 3;
        float* aggrow = aggbuf + (size_t)(qt * 64 + row) * CN;
        int   runc = lab[seg * 16];
        float runv = 0.0f;
        #pragma unroll
        for (int k = 0; k < 16; ++k) {
            int s = seg * 16 + k;
            int c = lab[s];
            if (c != runc) { atomicAdd(&aggrow[runc], runv); runv = 0.0f; runc = c; }
            runv += sc[row][s];
        }
        atomicAdd(&aggrow[runc], runv);
    }
}

// ---------------------------------------------------------------------------
// Finale A: grid 32 x 256 — one wave per query. Histogram counts in LDS,
// then per-wave: mean, fused max+argmax chain, exp-sum, per-q logprob+pred.
// ---------------------------------------------------------------------------
__global__ __launch_bounds__(256) void finale_kernel(
    const float* __restrict__ aggbuf, const int* __restrict__ labels,
    const int* __restrict__ tgt, float* __restrict__ lossp, float* __restrict__ out)
{
    __shared__ float cnt[CN];
    const int tid = threadIdx.x;
    if (tid < CN) cnt[tid] = 0.0f;
    __syncthreads();
    atomicAdd(&cnt[labels[tid]],       1.0f);
    atomicAdd(&cnt[labels[tid + 256]], 1.0f);
    __syncthreads();

    const int lane = tid & 63;
    const int q    = blockIdx.x * 4 + (tid >> 6);

    float v = aggbuf[(size_t)q * CN + lane] / fmaxf(cnt[lane], 1.0f);
    float av = v; int am = lane;
    #pragma unroll
    for (int off = 1; off < 64; off <<= 1) {
        float ov = __shfl_xor(av, off);
        int   oi = __shfl_xor(am, off);
        if (ov > av || (ov == av && oi < am)) { av = ov; am = oi; }
    }
    float m = av;
    float e = expf(v - m);
    #pragma unroll
    for (int off = 1; off < 64; off <<= 1)
        e += __shfl_xor(e, off);
    int t = tgt[q];
    float vt = __shfl(v, t, 64);
    if (lane == 0) {
        lossp[q] = vt - m - logf(e);          // logprob; negate+mean in B
        out[1 + q] = (am == t) ? 1.0f : 0.0f;
    }
}

// ---------------------------------------------------------------------------
// Finale B: 1 block x 128 — loss = -mean(logprob).
// ---------------------------------------------------------------------------
__global__ __launch_bounds__(128) void loss_kernel(
    const float* __restrict__ lossp, float* __restrict__ out)
{
    const int tid = threadIdx.x;
    float v = lossp[tid];
    #pragma unroll
    for (int off = 1; off < 64; off <<= 1)
        v += __shfl_xor(v, off);
    __shared__ float partial[2];
    if ((tid & 63) == 0) partial[tid >> 6] = v;
    __syncthreads();
    if (tid == 0) out[0] = -(partial[0] + partial[1]) / (float)QN;
}

extern "C" void kernel_launch(void* const* d_in, const int* in_sizes, int n_in,
                              void* d_out, int out_size, void* d_ws, size_t ws_size,
                              hipStream_t stream) {
    const float* query   = (const float*)d_in[0];
    const float* support = (const float*)d_in[1];
    const float* W1      = (const float*)d_in[2];
    const float* b1      = (const float*)d_in[3];
    const float* W2      = (const float*)d_in[4];
    // d_in[5] = b2: uniform shift, cancels under log_softmax/argmax -> unused
    const int* labels = (const int*)d_in[6];
    const int* tgt    = (const int*)d_in[7];

    float* ws     = (float*)d_ws;
    float* hqp    = ws;                    // KSPLIT*QN*TDN
    float* hsp    = hqp + HQP_ELEMS;       // KSPLIT*SN*TDN
    float* aggbuf = hsp + HSP_ELEMS;       // QN*CN   (zeroed by gemm)
    float* lossp  = aggbuf + QN * CN;      // QN      (zeroed by gemm)
    float* out    = (float*)d_out;

    hipLaunchKernelGGL(gemm_kernel, dim3(12, 5, 4), dim3(256), 0, stream,
                       query, support, W1, hqp, hsp, aggbuf);
    hipLaunchKernelGGL(score_kernel, dim3(16, 2, 8), dim3(256), 0, stream,
                       hqp, hsp, b1, W2, labels, aggbuf);
    hipLaunchKernelGGL(finale_kernel, dim3(32), dim3(256), 0, stream,
                       aggbuf, labels, tgt, lossp, out);
    hipLaunchKernelGGL(loss_kernel, dim3(1), dim3(128), 0, stream,
                       lossp, out);
}